// Round 3
// baseline (240.342 us; speedup 1.0000x reference)
//
#include <hip/hip_runtime.h>
#include <hip/hip_bf16.h>

typedef __attribute__((ext_vector_type(8))) short  short8;
typedef __attribute__((ext_vector_type(4))) float  float4v;
typedef __attribute__((ext_vector_type(4))) unsigned short ushort4v;

#define NC    8192
#define TPIX  784      // 28*28
#define NB    8

// ws layout (bytes)
#define WS_M2    0         // bf16 [784][160]  = 250880 B
#define WS_ZACC  262144    // f32  [8][784]    = 25088
#define WS_DACC  287232    // f32  [8][784]    = 25088
#define WS_ZPOS  312320    // f32  [8][25][25] = 20000
#define WS_ZERO_OFF 262144
#define WS_ZERO_LEN 70176

__device__ __forceinline__ unsigned short bf16rne(float f) {
    unsigned int u = __float_as_uint(f);
    u = (u + 0x7FFFu + ((u >> 16) & 1u)) >> 16;
    return (unsigned short)u;
}

// pack 8 f32 -> 8 bf16 (compiler emits v_cvt_pk_bf16_f32)
__device__ __forceinline__ short8 cvt8(float4v a, float4v b) {
    union { __hip_bfloat162 h[4]; short8 s; } u;
    u.h[0] = __float22bfloat162_rn(float2{a[0], a[1]});
    u.h[1] = __float22bfloat162_rn(float2{a[2], a[3]});
    u.h[2] = __float22bfloat162_rn(float2{b[0], b[1]});
    u.h[3] = __float22bfloat162_rn(float2{b[2], b[3]});
    return u.s;
}

// ---------------- kernel 1: M2' = 10 * K[y,v] * K[x,u], bf16 [784][160] ----------------
__global__ void k_init_m2(unsigned short* __restrict__ m2) {
    int p  = blockIdx.x;           // 0..783
    int sp = threadIdx.x;          // 0..159
    int y = p / 28, x = p % 28;
    float val = 0.f;
    if (sp < 144) {
        int v = sp / 12, u = sp % 12;
        float kyv = 0.f, kxu = 0.f;
        for (int a = 0; a < 25; ++a) {
            float ctc = 0.9f + 1.05f * (float)a;
            int   i0  = (int)ctc; float wt = ctc - (float)i0;
            float Ay  = (i0 == y) ? (1.f - wt) : ((i0 + 1 == y) ? wt : 0.f);
            float Ax  = (i0 == x) ? (1.f - wt) : ((i0 + 1 == x) ? wt : 0.f);
            float csc = 0.7f + 0.4f * (float)a;
            int   j0  = (int)csc; float wsv = csc - (float)j0;
            float Bv  = (j0 == v) ? (1.f - wsv) : ((j0 + 1 == v) ? wsv : 0.f);
            float Bu  = (j0 == u) ? (1.f - wsv) : ((j0 + 1 == u) ? wsv : 0.f);
            kyv += Ay * Bv;
            kxu += Ax * Bu;
        }
        val = 10.f * kyv * kxu;
    }
    m2[p * 160 + sp] = bf16rne(val);
}

// ---------------- kernel 2: main fused GEMM + teacher-softmax reduction (transposed) ----
// Yt[p][c] = sum_sp M2[p,sp] * S[c,sp].  A = M2 (regs, loop-invariant), B = student chunk.
// Lane (g,l15) owns (p = p0 + 4g + i, c = c0 + l15): teacher read is one float4/lane.
// grid (7 p-groups, 64 c-groups, 8 b) = 3584 blocks -> VGPR-limited 8 blocks/CU occupancy.
__launch_bounds__(256, 4)
__global__ void k_main(const float* __restrict__ teacher,
                       const float* __restrict__ student,
                       const float* __restrict__ center,
                       const unsigned short* __restrict__ m2,
                       float* __restrict__ zacc, float* __restrict__ dacc) {
    const int b  = blockIdx.z;
    const int cg = blockIdx.y;
    const int t  = threadIdx.x;
    const int w    = t >> 6;
    const int lane = t & 63;
    const int l15  = lane & 15;
    const int g    = lane >> 4;

    const int tile0 = (blockIdx.x * 4 + w) * 2;
    const bool va = (tile0     < 49);
    const bool vb = (tile0 + 1 < 49);
    const int p0a = va ? tile0 * 16 : 0;
    const int p0b = vb ? (tile0 + 1) * 16 : 0;

    // A fragments (M2 rows p0+l15), loop-invariant. Cols 144..159 are zeros in m2.
    short8 afa[5], afb[5];
    {
        const unsigned short* ra = m2 + (p0a + l15) * 160;
        const unsigned short* rb = m2 + (p0b + l15) * 160;
        #pragma unroll
        for (int ks = 0; ks < 5; ++ks) {
            afa[ks] = *(const short8*)(ra + ks * 32 + g * 8);
            afb[ks] = *(const short8*)(rb + ks * 32 + g * 8);
        }
    }

    float sEa[4] = {0.f, 0.f, 0.f, 0.f}, sEYa[4] = {0.f, 0.f, 0.f, 0.f};
    float sEb[4] = {0.f, 0.f, 0.f, 0.f}, sEYb[4] = {0.f, 0.f, 0.f, 0.f};

    const long long sbase = (long long)(b * NC) * 144;
    const long long tbase = (long long)(b * NC) * TPIX;
    const short8 zfrag = {0, 0, 0, 0, 0, 0, 0, 0};

    for (int cc = 0; cc < 8; ++cc) {
        const int c = cg * 128 + cc * 16 + l15;
        const float* srow = student + sbase + (long long)c * 144;

        // B fragments: student row c, K = 0..143 (+ zero pad to 160)
        short8 bf[5];
        #pragma unroll
        for (int ks = 0; ks < 4; ++ks)
            bf[ks] = cvt8(*(const float4v*)(srow + ks * 32 + g * 8),
                          *(const float4v*)(srow + ks * 32 + g * 8 + 4));
        bf[4] = (g < 2) ? cvt8(*(const float4v*)(srow + 128 + g * 8),
                               *(const float4v*)(srow + 128 + g * 8 + 4))
                        : zfrag;

        const float cen = center[c];
        const float* trow = teacher + tbase + (long long)c * TPIX;

        // ---- tile a ----
        {
            float4v tv = *(const float4v*)(trow + p0a + 4 * g);
            float4v acc = {0.f, 0.f, 0.f, 0.f};
            #pragma unroll
            for (int ks = 0; ks < 5; ++ks)
                acc = __builtin_amdgcn_mfma_f32_16x16x32_bf16(afa[ks], bf[ks], acc, 0, 0, 0);
            #pragma unroll
            for (int i = 0; i < 4; ++i) {
                float e = exp2f(fmaf(36.0673762f, tv[i] - cen, -233.7165966f));
                sEa[i] += e;
                sEYa[i] = fmaf(e, acc[i], sEYa[i]);
            }
        }
        // ---- tile b ----
        {
            float4v tv = *(const float4v*)(trow + p0b + 4 * g);
            float4v acc = {0.f, 0.f, 0.f, 0.f};
            #pragma unroll
            for (int ks = 0; ks < 5; ++ks)
                acc = __builtin_amdgcn_mfma_f32_16x16x32_bf16(afb[ks], bf[ks], acc, 0, 0, 0);
            #pragma unroll
            for (int i = 0; i < 4; ++i) {
                float e = exp2f(fmaf(36.0673762f, tv[i] - cen, -233.7165966f));
                sEb[i] += e;
                sEYb[i] = fmaf(e, acc[i], sEYb[i]);
            }
        }
    }

    // reduce over l15 (16 channels/chunk) and commit
    #pragma unroll
    for (int i = 0; i < 4; ++i) {
        float e0 = sEa[i], y0 = sEYa[i], e1 = sEb[i], y1 = sEYb[i];
        e0 += __shfl_xor(e0, 1); e0 += __shfl_xor(e0, 2); e0 += __shfl_xor(e0, 4); e0 += __shfl_xor(e0, 8);
        y0 += __shfl_xor(y0, 1); y0 += __shfl_xor(y0, 2); y0 += __shfl_xor(y0, 4); y0 += __shfl_xor(y0, 8);
        e1 += __shfl_xor(e1, 1); e1 += __shfl_xor(e1, 2); e1 += __shfl_xor(e1, 4); e1 += __shfl_xor(e1, 8);
        y1 += __shfl_xor(y1, 1); y1 += __shfl_xor(y1, 2); y1 += __shfl_xor(y1, 4); y1 += __shfl_xor(y1, 8);
        if (l15 == 0) {
            if (va) {
                atomicAdd(zacc + b * TPIX + p0a + 4 * g + i, e0);
                atomicAdd(dacc + b * TPIX + p0a + 4 * g + i, y0);
            }
            if (vb) {
                atomicAdd(zacc + b * TPIX + p0b + 4 * g + i, e1);
                atomicAdd(dacc + b * TPIX + p0b + 4 * g + i, y1);
            }
        }
    }
}

// ---------------- kernel 3: per-position LSE partials (register-only, no LDS) ----------
// grid (16 c-groups, 25 a, 8 b) = 3200 blocks; thread = 1 channel per j-iter (2 iters).
__launch_bounds__(256)
__global__ void k_lse(const float* __restrict__ student, float* __restrict__ zpos) {
    const int cg = blockIdx.x;
    const int a  = blockIdx.y;
    const int b  = blockIdx.z;
    const int t  = threadIdx.x;

    const float cv = 0.7f + 0.4f * (float)a;
    const int   v0 = (int)cv;
    const float wv = cv - (float)v0;
    const float W0 = 10.f * (1.f - wv), W1 = 10.f * wv;

    float accs[25];
    #pragma unroll
    for (int p = 0; p < 25; ++p) accs[p] = 0.f;

    #pragma unroll
    for (int j = 0; j < 2; ++j) {
        const int c = cg * 512 + 256 * j + t;
        const float* row = student + (long long)(b * NC + c) * 144 + v0 * 12;
        float4v r0 = *(const float4v*)(row + 0);
        float4v r1 = *(const float4v*)(row + 4);
        float4v r2 = *(const float4v*)(row + 8);
        float4v s0 = *(const float4v*)(row + 12);
        float4v s1 = *(const float4v*)(row + 16);
        float4v s2 = *(const float4v*)(row + 20);

        float R[12];
        #pragma unroll
        for (int u = 0; u < 4; ++u) {
            R[u]     = fmaf(W0, r0[u], W1 * s0[u]);
            R[u + 4] = fmaf(W0, r1[u], W1 * s1[u]);
            R[u + 8] = fmaf(W0, r2[u], W1 * s2[u]);
        }
        #pragma unroll
        for (int p = 0; p < 25; ++p) {
            const float cu = 0.7f + 0.4f * (float)p;   // const-folds
            const int   u0 = (int)cu;
            const float wu = cu - (float)u0;
            float sc = fmaf(1.f - wu, R[u0], wu * R[u0 + 1]);     // = 10*s_common
            accs[p] += exp2f(fmaf(1.44269504f, sc, -86.5617025f)); // exp(sc - 60)
        }
    }

    // full-wave reduce, then one lane commits
    #pragma unroll
    for (int p = 0; p < 25; ++p) {
        float v = accs[p];
        #pragma unroll
        for (int m = 1; m < 64; m <<= 1) v += __shfl_xor(v, m);
        accs[p] = v;
    }
    if ((t & 63) == 0) {
        #pragma unroll
        for (int p = 0; p < 25; ++p)
            atomicAdd(zpos + (b * 25 + a) * 25 + p, accs[p]);
    }
}

// ---------------- kernel 4: final combine ----------------
__global__ void k_final(const float* __restrict__ zacc, const float* __restrict__ dacc,
                        const float* __restrict__ zpos, float* __restrict__ out) {
    __shared__ float red[8];
    int t = threadIdx.x;   // 256
    float s = 0.f;
    for (int i = t; i < 5000; i += 256) s += 60.f + logf(zpos[i]);
    for (int i = t; i < NB * TPIX; i += 256) s -= dacc[i] / zacc[i];
    for (int m = 1; m < 64; m <<= 1) s += __shfl_xor(s, m);
    if ((t & 63) == 0) red[t >> 6] = s;
    __syncthreads();
    if (t == 0) out[0] = (red[0] + red[1] + red[2] + red[3]) * (1.f / 5000.f);
}

extern "C" void kernel_launch(void* const* d_in, const int* in_sizes, int n_in,
                              void* d_out, int out_size, void* d_ws, size_t ws_size,
                              hipStream_t stream) {
    const float* teacher = (const float*)d_in[0];
    const float* student = (const float*)d_in[1];
    const float* center  = (const float*)d_in[2];

    char* ws = (char*)d_ws;
    unsigned short* m2 = (unsigned short*)(ws + WS_M2);
    float* zacc = (float*)(ws + WS_ZACC);
    float* dacc = (float*)(ws + WS_DACC);
    float* zpos = (float*)(ws + WS_ZPOS);

    hipMemsetAsync(ws + WS_ZERO_OFF, 0, WS_ZERO_LEN, stream);
    k_init_m2<<<784, 160, 0, stream>>>(m2);
    k_main<<<dim3(7, 64, 8), 256, 0, stream>>>(teacher, student, center, m2, zacc, dacc);
    k_lse<<<dim3(16, 25, 8), 256, 0, stream>>>(student, zpos);
    k_final<<<1, 256, 0, stream>>>(zacc, dacc, zpos, (float*)d_out);
}

// Round 4
// 168.109 us; speedup vs baseline: 1.4297x; 1.4297x over previous
//
#include <hip/hip_runtime.h>
#include <hip/hip_bf16.h>

typedef __attribute__((ext_vector_type(8))) short  short8;
typedef __attribute__((ext_vector_type(4))) float  float4v;
typedef __attribute__((ext_vector_type(4))) unsigned short ushort4v;

#define NC    8192
#define TPIX  784      // 28*28
#define NB    8

// ws layout (bytes)
#define WS_M2    0         // bf16 [784][160]  = 250880 B
#define WS_ZACC  262144    // f32  [8][784]    = 25088
#define WS_DACC  287232    // f32  [8][784]    = 25088
#define WS_ZPOS  312320    // f32  [8][25][25] = 20000
#define WS_ZERO_OFF 262144
#define WS_ZERO_LEN 70176

__device__ __forceinline__ unsigned short bf16rne(float f) {
    unsigned int u = __float_as_uint(f);
    u = (u + 0x7FFFu + ((u >> 16) & 1u)) >> 16;
    return (unsigned short)u;
}

__device__ __forceinline__ short8 cvt8(float4v a, float4v b) {
    union { __hip_bfloat162 h[4]; short8 s; } u;
    u.h[0] = __float22bfloat162_rn(float2{a[0], a[1]});
    u.h[1] = __float22bfloat162_rn(float2{a[2], a[3]});
    u.h[2] = __float22bfloat162_rn(float2{b[0], b[1]});
    u.h[3] = __float22bfloat162_rn(float2{b[2], b[3]});
    return u.s;
}

// async global->LDS, 16 B per lane; LDS dest = wave-uniform base + lane*16 (HW rule)
__device__ __forceinline__ void dma16(const float* g, float* l) {
    __builtin_amdgcn_global_load_lds(
        (const __attribute__((address_space(1))) unsigned int*)g,
        (__attribute__((address_space(3))) unsigned int*)l, 16, 0, 0);
}

// ---------------- kernel 1: M2' = 10 * K[y,v] * K[x,u], bf16 [784][160] ----------------
__global__ void k_init_m2(unsigned short* __restrict__ m2) {
    int p  = blockIdx.x;           // 0..783
    int sp = threadIdx.x;          // 0..159
    int y = p / 28, x = p % 28;
    float val = 0.f;
    if (sp < 144) {
        int v = sp / 12, u = sp % 12;
        float kyv = 0.f, kxu = 0.f;
        for (int a = 0; a < 25; ++a) {
            float ctc = 0.9f + 1.05f * (float)a;
            int   i0  = (int)ctc; float wt = ctc - (float)i0;
            float Ay  = (i0 == y) ? (1.f - wt) : ((i0 + 1 == y) ? wt : 0.f);
            float Ax  = (i0 == x) ? (1.f - wt) : ((i0 + 1 == x) ? wt : 0.f);
            float csc = 0.7f + 0.4f * (float)a;
            int   j0  = (int)csc; float wsv = csc - (float)j0;
            float Bv  = (j0 == v) ? (1.f - wsv) : ((j0 + 1 == v) ? wsv : 0.f);
            float Bu  = (j0 == u) ? (1.f - wsv) : ((j0 + 1 == u) ? wsv : 0.f);
            kyv += Ay * Bv;
            kxu += Ax * Bu;
        }
        val = 10.f * kyv * kxu;
    }
    m2[p * 160 + sp] = bf16rne(val);
}

// ---------------- kernel 2: main — DMA-staged teacher, MFMA, fused softmax reduce ------
// grid (3 ph, 32 cg, 8 b) = 768 blocks, 512 thr (8 waves).
// Block: p-chunk [ph*256, +256) = 16 tiles (wave w owns tiles ph*16+2w, +1),
//        channels [cg*256, +256) in 16 iterations of 16.
// Teacher: global_load_lds, wave w stages rows (ch=w) and (ch=w+8) contiguously (1 KB each),
//          granule-XOR pre-swizzled source so epilogue ds_read_b128 is 2-way (free).
// Triple-buffered LDS, issue-ahead-2, counted vmcnt (never drains the pipeline).
__launch_bounds__(512, 2)
__global__ void k_main(const float* __restrict__ teacher,
                       const float* __restrict__ student,
                       const float* __restrict__ center,
                       const unsigned short* __restrict__ m2,
                       float* __restrict__ zacc, float* __restrict__ dacc) {
    __shared__ float tlds[3][4096];   // 3 bufs x 16 ch x 256 p (f32), XOR-swizzled granules

    const int b  = blockIdx.z;
    const int cg = blockIdx.y;        // 0..31
    const int ph = blockIdx.x;        // 0..2
    const int t  = threadIdx.x;
    const int w = t >> 6, lane = t & 63, l15 = lane & 15, g = lane >> 4;

    const long long tbase = (long long)(b * NC) * TPIX;
    const long long sbase = (long long)(b * NC) * 144;
    const int c0 = cg * 256;

    // A fragments: tiles Ta = ph*16 + 2w, Tb = Ta+1 (rows p = T*16 + l15), loop-invariant
    const int Ta = ph * 16 + 2 * w;
    short8 afa[5], afb[5];
    {
        const unsigned short* ra = m2 + (Ta * 16 + l15) * 160;
        const unsigned short* rb = m2 + ((Ta + 1) * 16 + l15) * 160;
        #pragma unroll
        for (int ks = 0; ks < 5; ++ks) {
            afa[ks] = *(const short8*)(ra + ks * 32 + g * 8);
            afb[ks] = *(const short8*)(rb + ks * 32 + g * 8);
        }
    }

    // teacher DMA sources: wave w stages channels w and w+8 of each 16-ch set.
    // LDS granule q of row ch holds teacher granule q ^ (ch&7)  (involution).
    const int ch0 = w, ch1 = w + 8;
    const float* tsrc0 = teacher + tbase + (long long)(c0 + ch0) * TPIX + ph * 256 + ((lane ^ (ch0 & 7)) << 2);
    const float* tsrc1 = teacher + tbase + (long long)(c0 + ch1) * TPIX + ph * 256 + ((lane ^ (ch1 & 7)) << 2);
    const long long cstep = 16LL * TPIX;   // advance 16 channels per iteration

    float sEa[4] = {0.f,0.f,0.f,0.f}, sEYa[4] = {0.f,0.f,0.f,0.f};
    float sEb[4] = {0.f,0.f,0.f,0.f}, sEYb[4] = {0.f,0.f,0.f,0.f};
    const short8 zfrag = {0,0,0,0,0,0,0,0};

    // prologue: stage T(0)->buf0, T(1)->buf1
    dma16(tsrc0,             &tlds[0][ch0 * 256]);
    dma16(tsrc1,             &tlds[0][ch1 * 256]);
    dma16(tsrc0 + cstep,     &tlds[1][ch0 * 256]);
    dma16(tsrc1 + cstep,     &tlds[1][ch1 * 256]);

    for (int cc = 0; cc < 16; ++cc) {
        __builtin_amdgcn_s_barrier();                       // A: buf[(cc+2)%3] free for rewrite
        const int cbase = c0 + cc * 16;
        const float* srow = student + sbase + (long long)(cbase + l15) * 144;

        // student raw loads (oldest in vmcnt queue)
        float4v s0 = *(const float4v*)(srow + 0);
        float4v s1 = *(const float4v*)(srow + 4);
        float4v s2 = *(const float4v*)(srow + 32 + 0);
        float4v s3 = *(const float4v*)(srow + 32 + 4);
        float4v s4 = *(const float4v*)(srow + 64 + 0);
        float4v s5 = *(const float4v*)(srow + 64 + 4);
        float4v s6 = *(const float4v*)(srow + 96 + 0);
        float4v s7 = *(const float4v*)(srow + 96 + 4);
        float4v s8 = {0.f,0.f,0.f,0.f}, s9 = {0.f,0.f,0.f,0.f};
        if (g < 2) {
            s8 = *(const float4v*)(srow + 128 + 0);
            s9 = *(const float4v*)(srow + 128 + 4);
        }
        const float cen = center[cbase + l15];

        __builtin_amdgcn_sched_barrier(0);
        // issue T(cc+2) (newest in queue; stays in flight across MFMA + next iter)
        {
            const int ccn = (cc + 2 < 16) ? cc + 2 : 15;
            const int bw2 = (cc + 2) % 3;
            dma16(tsrc0 + (long long)ccn * cstep, &tlds[bw2][ch0 * 256]);
            dma16(tsrc1 + (long long)ccn * cstep, &tlds[bw2][ch1 * 256]);
        }
        __builtin_amdgcn_sched_barrier(0);

        // B fragments (the two g-dependent layouts match: lane needs k = ks*32 + g*8)
        short8 bf[5];
        bf[0] = cvt8(s0, s1);
        bf[1] = cvt8(s2, s3);
        bf[2] = cvt8(s4, s5);
        bf[3] = cvt8(s6, s7);
        bf[4] = (g < 2) ? cvt8(s8, s9) : zfrag;

        float4v acca = {0.f,0.f,0.f,0.f}, accb = {0.f,0.f,0.f,0.f};
        #pragma unroll
        for (int ks = 0; ks < 5; ++ks) {
            acca = __builtin_amdgcn_mfma_f32_16x16x32_bf16(afa[ks], bf[ks], acca, 0, 0, 0);
            accb = __builtin_amdgcn_mfma_f32_16x16x32_bf16(afb[ks], bf[ks], accb, 0, 0, 0);
        }

        // only the 2 T(cc+2) DMAs may remain outstanding; T(cc) retired long ago
        __builtin_amdgcn_sched_barrier(0);
        asm volatile("s_waitcnt vmcnt(2)" ::: "memory");
        __builtin_amdgcn_sched_barrier(0);
        __builtin_amdgcn_s_barrier();                       // B: buf[cc%3] ready for all waves
        __builtin_amdgcn_sched_barrier(0);

        // teacher from LDS: lane (g,l15) owns (p = T*16 + 4g + i, c = cbase + l15)
        const int br = cc % 3;
        const float* Tp = &tlds[br][l15 * 256];
        const int qa = (2 * w)     * 4 + g;    // granule index of tile a
        const int qb = (2 * w + 1) * 4 + g;
        float4v tva = *(const float4v*)(Tp + (((qa ^ (l15 & 7)) << 2)));
        float4v tvb = *(const float4v*)(Tp + (((qb ^ (l15 & 7)) << 2)));

        #pragma unroll
        for (int i = 0; i < 4; ++i) {
            float ea = exp2f(fmaf(36.0673762f, tva[i] - cen, -233.7165966f));
            sEa[i] += ea;
            sEYa[i] = fmaf(ea, acca[i], sEYa[i]);
            float eb = exp2f(fmaf(36.0673762f, tvb[i] - cen, -233.7165966f));
            sEb[i] += eb;
            sEYb[i] = fmaf(eb, accb[i], sEYb[i]);
        }
    }

    // reduce over l15 (16 channels) and commit
    #pragma unroll
    for (int i = 0; i < 4; ++i) {
        float e0 = sEa[i], y0 = sEYa[i], e1 = sEb[i], y1 = sEYb[i];
        e0 += __shfl_xor(e0, 1); e0 += __shfl_xor(e0, 2); e0 += __shfl_xor(e0, 4); e0 += __shfl_xor(e0, 8);
        y0 += __shfl_xor(y0, 1); y0 += __shfl_xor(y0, 2); y0 += __shfl_xor(y0, 4); y0 += __shfl_xor(y0, 8);
        e1 += __shfl_xor(e1, 1); e1 += __shfl_xor(e1, 2); e1 += __shfl_xor(e1, 4); e1 += __shfl_xor(e1, 8);
        y1 += __shfl_xor(y1, 1); y1 += __shfl_xor(y1, 2); y1 += __shfl_xor(y1, 4); y1 += __shfl_xor(y1, 8);
        if (l15 == 0) {
            atomicAdd(zacc + b * TPIX + Ta * 16 + 4 * g + i, e0);
            atomicAdd(dacc + b * TPIX + Ta * 16 + 4 * g + i, y0);
            atomicAdd(zacc + b * TPIX + (Ta + 1) * 16 + 4 * g + i, e1);
            atomicAdd(dacc + b * TPIX + (Ta + 1) * 16 + 4 * g + i, y1);
        }
    }
}

// ---------------- kernel 2b: tail — tile 48 (p 768..783), scatter path, tiny ----------
__launch_bounds__(256, 4)
__global__ void k_tail(const float* __restrict__ teacher,
                       const float* __restrict__ student,
                       const float* __restrict__ center,
                       const unsigned short* __restrict__ m2,
                       float* __restrict__ zacc, float* __restrict__ dacc) {
    const int b   = blockIdx.y;
    const int cgi = blockIdx.x;       // 16 groups of 512 channels
    const int t   = threadIdx.x;
    const int w = t >> 6, lane = t & 63, l15 = lane & 15, g = lane >> 4;

    short8 af[5];
    #pragma unroll
    for (int ks = 0; ks < 5; ++ks)
        af[ks] = *(const short8*)(m2 + (768 + l15) * 160 + ks * 32 + g * 8);

    float sE[4] = {0.f,0.f,0.f,0.f}, sEY[4] = {0.f,0.f,0.f,0.f};
    const short8 zfrag = {0,0,0,0,0,0,0,0};

    for (int cc = 0; cc < 8; ++cc) {
        const int c = cgi * 512 + cc * 64 + w * 16 + l15;
        const float* srow = student + (long long)(b * NC + c) * 144;
        short8 bf[5];
        #pragma unroll
        for (int ks = 0; ks < 4; ++ks)
            bf[ks] = cvt8(*(const float4v*)(srow + ks * 32),
                          *(const float4v*)(srow + ks * 32 + 4));
        bf[4] = (g < 2) ? cvt8(*(const float4v*)(srow + 128),
                               *(const float4v*)(srow + 128 + 4)) : zfrag;
        const float cen = center[c];
        float4v tv = *(const float4v*)(teacher + (long long)(b * NC + c) * TPIX + 768 + 4 * g);
        float4v acc = {0.f,0.f,0.f,0.f};
        #pragma unroll
        for (int ks = 0; ks < 5; ++ks)
            acc = __builtin_amdgcn_mfma_f32_16x16x32_bf16(af[ks], bf[ks], acc, 0, 0, 0);
        #pragma unroll
        for (int i = 0; i < 4; ++i) {
            float e = exp2f(fmaf(36.0673762f, tv[i] - cen, -233.7165966f));
            sE[i] += e;
            sEY[i] = fmaf(e, acc[i], sEY[i]);
        }
    }

    #pragma unroll
    for (int i = 0; i < 4; ++i) {
        float e = sE[i], y = sEY[i];
        e += __shfl_xor(e, 1); e += __shfl_xor(e, 2); e += __shfl_xor(e, 4); e += __shfl_xor(e, 8);
        y += __shfl_xor(y, 1); y += __shfl_xor(y, 2); y += __shfl_xor(y, 4); y += __shfl_xor(y, 8);
        if (l15 == 0) {
            atomicAdd(zacc + b * TPIX + 768 + 4 * g + i, e);
            atomicAdd(dacc + b * TPIX + 768 + 4 * g + i, y);
        }
    }
}

// ---------------- kernel 3: per-position LSE partials (register-only; R2 shape) -------
__launch_bounds__(256)
__global__ void k_lse(const float* __restrict__ student, float* __restrict__ zpos) {
    const int cg = blockIdx.x;   // 0..3
    const int a  = blockIdx.y;
    const int b  = blockIdx.z;
    const int t  = threadIdx.x;

    const float cv = 0.7f + 0.4f * (float)a;
    const int   v0 = (int)cv;
    const float wv = cv - (float)v0;
    const float W0 = 10.f * (1.f - wv), W1 = 10.f * wv;

    float accs[25];
    #pragma unroll
    for (int p = 0; p < 25; ++p) accs[p] = 0.f;

    for (int j = 0; j < 8; ++j) {
        const int c = cg * 2048 + 256 * j + t;
        const float* row = student + (long long)(b * NC + c) * 144 + v0 * 12;
        float4v r0 = *(const float4v*)(row + 0);
        float4v r1 = *(const float4v*)(row + 4);
        float4v r2 = *(const float4v*)(row + 8);
        float4v s0 = *(const float4v*)(row + 12);
        float4v s1 = *(const float4v*)(row + 16);
        float4v s2 = *(const float4v*)(row + 20);

        float R[12];
        #pragma unroll
        for (int u = 0; u < 4; ++u) {
            R[u]     = fmaf(W0, r0[u], W1 * s0[u]);
            R[u + 4] = fmaf(W0, r1[u], W1 * s1[u]);
            R[u + 8] = fmaf(W0, r2[u], W1 * s2[u]);
        }
        #pragma unroll
        for (int p = 0; p < 25; ++p) {
            const float cu = 0.7f + 0.4f * (float)p;
            const int   u0 = (int)cu;
            const float wu = cu - (float)u0;
            float sc = fmaf(1.f - wu, R[u0], wu * R[u0 + 1]);       // = 10*s_common
            accs[p] += exp2f(fmaf(1.44269504f, sc, -86.5617025f));  // exp(sc - 60)
        }
    }

    #pragma unroll
    for (int p = 0; p < 25; ++p) {
        float v = accs[p];
        #pragma unroll
        for (int m = 1; m < 64; m <<= 1) v += __shfl_xor(v, m);
        accs[p] = v;
    }
    if ((t & 63) == 0) {
        #pragma unroll
        for (int p = 0; p < 25; ++p)
            atomicAdd(zpos + (b * 25 + a) * 25 + p, accs[p]);
    }
}

// ---------------- kernel 4: final combine ----------------
__global__ void k_final(const float* __restrict__ zacc, const float* __restrict__ dacc,
                        const float* __restrict__ zpos, float* __restrict__ out) {
    __shared__ float red[8];
    int t = threadIdx.x;   // 256
    float s = 0.f;
    for (int i = t; i < 5000; i += 256) s += 60.f + logf(zpos[i]);
    for (int i = t; i < NB * TPIX; i += 256) s -= dacc[i] / zacc[i];
    for (int m = 1; m < 64; m <<= 1) s += __shfl_xor(s, m);
    if ((t & 63) == 0) red[t >> 6] = s;
    __syncthreads();
    if (t == 0) out[0] = (red[0] + red[1] + red[2] + red[3]) * (1.f / 5000.f);
}

extern "C" void kernel_launch(void* const* d_in, const int* in_sizes, int n_in,
                              void* d_out, int out_size, void* d_ws, size_t ws_size,
                              hipStream_t stream) {
    const float* teacher = (const float*)d_in[0];
    const float* student = (const float*)d_in[1];
    const float* center  = (const float*)d_in[2];

    char* ws = (char*)d_ws;
    unsigned short* m2 = (unsigned short*)(ws + WS_M2);
    float* zacc = (float*)(ws + WS_ZACC);
    float* dacc = (float*)(ws + WS_DACC);
    float* zpos = (float*)(ws + WS_ZPOS);

    hipMemsetAsync(ws + WS_ZERO_OFF, 0, WS_ZERO_LEN, stream);
    k_init_m2<<<784, 160, 0, stream>>>(m2);
    k_main<<<dim3(3, 32, 8), 512, 0, stream>>>(teacher, student, center, m2, zacc, dacc);
    k_tail<<<dim3(16, 8), 256, 0, stream>>>(teacher, student, center, m2, zacc, dacc);
    k_lse<<<dim3(4, 25, 8), 256, 0, stream>>>(student, zpos);
    k_final<<<1, 256, 0, stream>>>(zacc, dacc, zpos, (float*)d_out);
}

// Round 5
// 156.002 us; speedup vs baseline: 1.5406x; 1.0776x over previous
//
#include <hip/hip_runtime.h>
#include <hip/hip_bf16.h>

typedef __attribute__((ext_vector_type(8))) short  short8;
typedef __attribute__((ext_vector_type(4))) float  float4v;
typedef __attribute__((ext_vector_type(4))) unsigned short ushort4v;

#define NC    8192
#define TPIX  784      // 28*28
#define NB    8

// ws layout (bytes)
#define WS_M2    0                 // bf16 [784][160]   = 250880
#define WS_O     250880            // f32  [8192]       = 32768
#define WS_ZACC  283648            // f32  [8][784]     = 25088
#define WS_DACC  308736            // f32  [8][784]     = 25088
#define WS_ZPOS  333824            // f32  [8][25][25]  = 20000
#define WS_ZERO_OFF WS_ZACC
#define WS_ZERO_LEN 70176
#define WS_STUDB 360448            // bf16 [65536][160] = 20971520
#define WS_NEED  (360448 + 65536*320)

__device__ __forceinline__ unsigned short bf16rne(float f) {
    unsigned int u = __float_as_uint(f);
    u = (u + 0x7FFFu + ((u >> 16) & 1u)) >> 16;
    return (unsigned short)u;
}

__device__ __forceinline__ short8 cvt8(float4v a, float4v b) {
    union { __hip_bfloat162 h[4]; short8 s; } u;
    u.h[0] = __float22bfloat162_rn(float2{a[0], a[1]});
    u.h[1] = __float22bfloat162_rn(float2{a[2], a[3]});
    u.h[2] = __float22bfloat162_rn(float2{b[0], b[1]});
    u.h[3] = __float22bfloat162_rn(float2{b[2], b[3]});
    return u.s;
}

// ---------------- kernel 1: M2' = 10 * K[y,v] * K[x,u], bf16 [784][160] ----------------
__global__ void k_init_m2(unsigned short* __restrict__ m2) {
    int p  = blockIdx.x;           // 0..783
    int sp = threadIdx.x;          // 0..159
    int y = p / 28, x = p % 28;
    float val = 0.f;
    if (sp < 144) {
        int v = sp / 12, u = sp % 12;
        float kyv = 0.f, kxu = 0.f;
        for (int a = 0; a < 25; ++a) {
            float ctc = 0.9f + 1.05f * (float)a;
            int   i0  = (int)ctc; float wt = ctc - (float)i0;
            float Ay  = (i0 == y) ? (1.f - wt) : ((i0 + 1 == y) ? wt : 0.f);
            float Ax  = (i0 == x) ? (1.f - wt) : ((i0 + 1 == x) ? wt : 0.f);
            float csc = 0.7f + 0.4f * (float)a;
            int   j0  = (int)csc; float wsv = csc - (float)j0;
            float Bv  = (j0 == v) ? (1.f - wsv) : ((j0 + 1 == v) ? wsv : 0.f);
            float Bu  = (j0 == u) ? (1.f - wsv) : ((j0 + 1 == u) ? wsv : 0.f);
            kyv += Ay * Bv;
            kxu += Ax * Bu;
        }
        val = 10.f * kyv * kxu;
    }
    m2[p * 160 + sp] = bf16rne(val);
}

// ---------------- kernel 1b: pre-convert student -> padded bf16 [65536][160], o[c] -----
// thread = one 16 B output chunk (8 bf16 from 32 B f32 input); 65536 rows x 20 chunks.
__launch_bounds__(256)
__global__ void k_pre(const float* __restrict__ student, const float* __restrict__ center,
                      unsigned short* __restrict__ studb, float* __restrict__ o) {
    const int tid = blockIdx.x * 256 + threadIdx.x;   // 0 .. 1310719
    const int row = tid / 20, ch = tid % 20;
    short8 hv = {0,0,0,0,0,0,0,0};
    if (ch < 18) {
        const float* src = student + (long long)row * 144 + ch * 8;
        hv = cvt8(*(const float4v*)(src), *(const float4v*)(src + 4));
    }
    *(short8*)(studb + (long long)row * 160 + ch * 8) = hv;
    if (ch == 0 && row < NC)
        o[row] = fmaf(36.0673762f, center[row], 233.7165966f);
}

// ---------------- kernel 2: main fused GEMM + teacher-softmax reduction ----------------
// Wave-independent (no LDS/barriers). Wave owns 2 p-tiles; lane (g,l15) owns
// (p = p0 + 4g + i, c = cbase + l15). cc unrolled x2: 16 independent loads batched
// (10 student-bf16 dwordx4 + 2 o + 4 teacher float4) before any consumption.
// grid (7 px, 32 cg, 8 b) = 1792 blocks, 256 thr.
template<bool PRE>
__launch_bounds__(256, 2)
__global__ void k_main(const float* __restrict__ teacher,
                       const float* __restrict__ student,
                       const float* __restrict__ center,
                       const unsigned short* __restrict__ m2,
                       const unsigned short* __restrict__ studb,
                       const float* __restrict__ o,
                       float* __restrict__ zacc, float* __restrict__ dacc) {
    const int b  = blockIdx.z;
    const int cg = blockIdx.y;        // 0..31 (256 channels per block)
    const int t  = threadIdx.x;
    const int w = t >> 6, lane = t & 63, l15 = lane & 15, g = lane >> 4;

    const int tile0 = (blockIdx.x * 4 + w) * 2;
    const bool va = (tile0     < 49);
    const bool vb = (tile0 + 1 < 49);
    const int p0a = va ? tile0 * 16 : 0;
    const int p0b = vb ? (tile0 + 1) * 16 : 0;

    // A fragments (M2 rows p0+l15), loop-invariant
    short8 afa[5], afb[5];
    {
        const unsigned short* ra = m2 + (p0a + l15) * 160;
        const unsigned short* rb = m2 + (p0b + l15) * 160;
        #pragma unroll
        for (int ks = 0; ks < 5; ++ks) {
            afa[ks] = *(const short8*)(ra + ks * 32 + g * 8);
            afb[ks] = *(const short8*)(rb + ks * 32 + g * 8);
        }
    }

    float sEa[4] = {0.f,0.f,0.f,0.f}, sEYa[4] = {0.f,0.f,0.f,0.f};
    float sEb[4] = {0.f,0.f,0.f,0.f}, sEYb[4] = {0.f,0.f,0.f,0.f};

    const long long tbase = (long long)(b * NC) * TPIX;
    const long long sbase = (long long)(b * NC) * 144;
    const short8 zfrag = {0,0,0,0,0,0,0,0};

    for (int cc = 0; cc < 8; ++cc) {
        const int cA = cg * 256 + cc * 32 + l15;   // u=0 channel
        const int cB = cA + 16;                    // u=1 channel

        // ---- issue all independent loads for this unrolled iteration ----
        short8 bfA[5], bfB[5];
        float oA, oB;
        if (PRE) {
            const unsigned short* rA = studb + ((long long)(b * NC) + cA) * 160;
            const unsigned short* rB = rA + 16 * 160;
            #pragma unroll
            for (int ks = 0; ks < 5; ++ks) {
                bfA[ks] = *(const short8*)(rA + ks * 32 + g * 8);
                bfB[ks] = *(const short8*)(rB + ks * 32 + g * 8);
            }
            oA = o[cA];
            oB = o[cB];
        } else {
            const float* sA = student + sbase + (long long)cA * 144;
            const float* sB = sA + 16 * 144;
            #pragma unroll
            for (int ks = 0; ks < 4; ++ks) {
                bfA[ks] = cvt8(*(const float4v*)(sA + ks * 32 + g * 8),
                               *(const float4v*)(sA + ks * 32 + g * 8 + 4));
                bfB[ks] = cvt8(*(const float4v*)(sB + ks * 32 + g * 8),
                               *(const float4v*)(sB + ks * 32 + g * 8 + 4));
            }
            bfA[4] = (g < 2) ? cvt8(*(const float4v*)(sA + 128 + g * 8),
                                    *(const float4v*)(sA + 128 + g * 8 + 4)) : zfrag;
            bfB[4] = (g < 2) ? cvt8(*(const float4v*)(sB + 128 + g * 8),
                                    *(const float4v*)(sB + 128 + g * 8 + 4)) : zfrag;
            oA = fmaf(36.0673762f, center[cA], 233.7165966f);
            oB = fmaf(36.0673762f, center[cB], 233.7165966f);
        }

        const float* trA = teacher + tbase + (long long)cA * TPIX;
        const float* trB = trA + 16LL * TPIX;
        float4v tvAa = *(const float4v*)(trA + p0a + 4 * g);
        float4v tvAb = *(const float4v*)(trA + p0b + 4 * g);
        float4v tvBa = *(const float4v*)(trB + p0a + 4 * g);
        float4v tvBb = *(const float4v*)(trB + p0b + 4 * g);

        // ---- compute ----
        float4v accAa = {0.f,0.f,0.f,0.f}, accAb = {0.f,0.f,0.f,0.f};
        float4v accBa = {0.f,0.f,0.f,0.f}, accBb = {0.f,0.f,0.f,0.f};
        #pragma unroll
        for (int ks = 0; ks < 5; ++ks) {
            accAa = __builtin_amdgcn_mfma_f32_16x16x32_bf16(afa[ks], bfA[ks], accAa, 0, 0, 0);
            accAb = __builtin_amdgcn_mfma_f32_16x16x32_bf16(afb[ks], bfA[ks], accAb, 0, 0, 0);
            accBa = __builtin_amdgcn_mfma_f32_16x16x32_bf16(afa[ks], bfB[ks], accBa, 0, 0, 0);
            accBb = __builtin_amdgcn_mfma_f32_16x16x32_bf16(afb[ks], bfB[ks], accBb, 0, 0, 0);
        }

        #pragma unroll
        for (int i = 0; i < 4; ++i) {
            float e0 = exp2f(fmaf(36.0673762f, tvAa[i], -oA));
            sEa[i] += e0;  sEYa[i] = fmaf(e0, accAa[i], sEYa[i]);
            float e1 = exp2f(fmaf(36.0673762f, tvAb[i], -oA));
            sEb[i] += e1;  sEYb[i] = fmaf(e1, accAb[i], sEYb[i]);
            float e2 = exp2f(fmaf(36.0673762f, tvBa[i], -oB));
            sEa[i] += e2;  sEYa[i] = fmaf(e2, accBa[i], sEYa[i]);
            float e3 = exp2f(fmaf(36.0673762f, tvBb[i], -oB));
            sEb[i] += e3;  sEYb[i] = fmaf(e3, accBb[i], sEYb[i]);
        }
    }

    // reduce over l15 (channels) and commit
    #pragma unroll
    for (int i = 0; i < 4; ++i) {
        float e0 = sEa[i], y0 = sEYa[i], e1 = sEb[i], y1 = sEYb[i];
        e0 += __shfl_xor(e0, 1); e0 += __shfl_xor(e0, 2); e0 += __shfl_xor(e0, 4); e0 += __shfl_xor(e0, 8);
        y0 += __shfl_xor(y0, 1); y0 += __shfl_xor(y0, 2); y0 += __shfl_xor(y0, 4); y0 += __shfl_xor(y0, 8);
        e1 += __shfl_xor(e1, 1); e1 += __shfl_xor(e1, 2); e1 += __shfl_xor(e1, 4); e1 += __shfl_xor(e1, 8);
        y1 += __shfl_xor(y1, 1); y1 += __shfl_xor(y1, 2); y1 += __shfl_xor(y1, 4); y1 += __shfl_xor(y1, 8);
        if (l15 == 0) {
            if (va) {
                atomicAdd(zacc + b * TPIX + p0a + 4 * g + i, e0);
                atomicAdd(dacc + b * TPIX + p0a + 4 * g + i, y0);
            }
            if (vb) {
                atomicAdd(zacc + b * TPIX + p0b + 4 * g + i, e1);
                atomicAdd(dacc + b * TPIX + p0b + 4 * g + i, y1);
            }
        }
    }
}

// ---------------- kernel 3: per-position LSE partials (register-only, no LDS) ----------
__launch_bounds__(256)
__global__ void k_lse(const float* __restrict__ student, float* __restrict__ zpos) {
    const int cg = blockIdx.x;   // 0..3
    const int a  = blockIdx.y;
    const int b  = blockIdx.z;
    const int t  = threadIdx.x;

    const float cv = 0.7f + 0.4f * (float)a;
    const int   v0 = (int)cv;
    const float wv = cv - (float)v0;
    const float W0 = 10.f * (1.f - wv), W1 = 10.f * wv;

    float accs[25];
    #pragma unroll
    for (int p = 0; p < 25; ++p) accs[p] = 0.f;

    for (int j = 0; j < 8; ++j) {
        const int c = cg * 2048 + 256 * j + t;
        const float* row = student + (long long)(b * NC + c) * 144 + v0 * 12;
        float4v r0 = *(const float4v*)(row + 0);
        float4v r1 = *(const float4v*)(row + 4);
        float4v r2 = *(const float4v*)(row + 8);
        float4v s0 = *(const float4v*)(row + 12);
        float4v s1 = *(const float4v*)(row + 16);
        float4v s2 = *(const float4v*)(row + 20);

        float R[12];
        #pragma unroll
        for (int u = 0; u < 4; ++u) {
            R[u]     = fmaf(W0, r0[u], W1 * s0[u]);
            R[u + 4] = fmaf(W0, r1[u], W1 * s1[u]);
            R[u + 8] = fmaf(W0, r2[u], W1 * s2[u]);
        }
        #pragma unroll
        for (int p = 0; p < 25; ++p) {
            const float cu = 0.7f + 0.4f * (float)p;
            const int   u0 = (int)cu;
            const float wu = cu - (float)u0;
            float sc = fmaf(1.f - wu, R[u0], wu * R[u0 + 1]);       // = 10*s_common
            accs[p] += exp2f(fmaf(1.44269504f, sc, -86.5617025f));  // exp(sc - 60)
        }
    }

    #pragma unroll
    for (int p = 0; p < 25; ++p) {
        float v = accs[p];
        #pragma unroll
        for (int m = 1; m < 64; m <<= 1) v += __shfl_xor(v, m);
        accs[p] = v;
    }
    if ((t & 63) == 0) {
        #pragma unroll
        for (int p = 0; p < 25; ++p)
            atomicAdd(zpos + (b * 25 + a) * 25 + p, accs[p]);
    }
}

// ---------------- kernel 4: final combine ----------------
__global__ void k_final(const float* __restrict__ zacc, const float* __restrict__ dacc,
                        const float* __restrict__ zpos, float* __restrict__ out) {
    __shared__ float red[8];
    int t = threadIdx.x;   // 256
    float s = 0.f;
    for (int i = t; i < 5000; i += 256) s += 60.f + logf(zpos[i]);
    for (int i = t; i < NB * TPIX; i += 256) s -= dacc[i] / zacc[i];
    for (int m = 1; m < 64; m <<= 1) s += __shfl_xor(s, m);
    if ((t & 63) == 0) red[t >> 6] = s;
    __syncthreads();
    if (t == 0) out[0] = (red[0] + red[1] + red[2] + red[3]) * (1.f / 5000.f);
}

extern "C" void kernel_launch(void* const* d_in, const int* in_sizes, int n_in,
                              void* d_out, int out_size, void* d_ws, size_t ws_size,
                              hipStream_t stream) {
    const float* teacher = (const float*)d_in[0];
    const float* student = (const float*)d_in[1];
    const float* center  = (const float*)d_in[2];

    char* ws = (char*)d_ws;
    unsigned short* m2    = (unsigned short*)(ws + WS_M2);
    float*          oarr  = (float*)(ws + WS_O);
    float*          zacc  = (float*)(ws + WS_ZACC);
    float*          dacc  = (float*)(ws + WS_DACC);
    float*          zpos  = (float*)(ws + WS_ZPOS);
    unsigned short* studb = (unsigned short*)(ws + WS_STUDB);

    hipMemsetAsync(ws + WS_ZERO_OFF, 0, WS_ZERO_LEN, stream);
    k_init_m2<<<784, 160, 0, stream>>>(m2);

    if (ws_size >= (size_t)WS_NEED) {
        k_pre<<<5120, 256, 0, stream>>>(student, center, studb, oarr);
        k_main<true><<<dim3(7, 32, 8), 256, 0, stream>>>(teacher, student, center, m2,
                                                         studb, oarr, zacc, dacc);
    } else {
        k_main<false><<<dim3(7, 32, 8), 256, 0, stream>>>(teacher, student, center, m2,
                                                          studb, oarr, zacc, dacc);
    }
    k_lse<<<dim3(4, 25, 8), 256, 0, stream>>>(student, zpos);
    k_final<<<1, 256, 0, stream>>>(zacc, dacc, zpos, (float*)d_out);
}